// Round 6
// baseline (350.455 us; speedup 1.0000x reference)
//
#include <hip/hip_runtime.h>
#include <cstdint>
#include <cstddef>

// MI355X self-attention: B=4 S=2048 E=1024 H=16 D=64
// R6: LDS double-buffering (1 barrier/tile, loads hidden behind compute) in
//     both GEMMs and attn; XCD-ownership swizzle in GEMMs (per-XCD A slice
//     2MB L2-resident, B-tile fetched once per XCD); attn block order
//     qblk-major per bh (K/V hot set ~1MB not 4MB).

typedef __attribute__((ext_vector_type(8))) short short8;   // 8 x bf16
typedef __attribute__((ext_vector_type(4))) float float4_;
typedef unsigned int u32;
typedef unsigned short u16;

__device__ __forceinline__ u16 f2b(float f) {
  u32 u = __float_as_uint(f);
  u += 0x7FFFu + ((u >> 16) & 1u);   // RNE
  return (u16)(u >> 16);
}

__device__ __forceinline__ float fexp2(float x) {
#if __has_builtin(__builtin_amdgcn_exp2f)
  return __builtin_amdgcn_exp2f(x);   // bare v_exp_f32
#else
  return exp2f(x);
#endif
}

// pack (lo,hi) floats -> bf16x2 by truncation (1 v_perm)
__device__ __forceinline__ u32 pk_trunc(float lo, float hi) {
#if __has_builtin(__builtin_amdgcn_perm)
  return __builtin_amdgcn_perm(__float_as_uint(hi), __float_as_uint(lo), 0x07060302);
#else
  return (__float_as_uint(hi) & 0xFFFF0000u) | (__float_as_uint(lo) >> 16);
#endif
}

// async global->LDS, 16B per lane; LDS dst must be wave-uniform base + lane*16
__device__ __forceinline__ void async_cp16(const void* g, void* l) {
  __builtin_amdgcn_global_load_lds(
      (const __attribute__((address_space(1))) u32*)g,
      (__attribute__((address_space(3))) u32*)l, 16, 0, 0);
}

// ---------------- pre-pass kernels ----------------

__global__ void cvt_x_bf16(const float* __restrict__ in, u16* __restrict__ out, int n4) {
  int i = blockIdx.x * 256 + threadIdx.x;
  if (i >= n4) return;
  float4 v = ((const float4*)in)[i];
  uint2 p;
  p.x = (u32)f2b(v.x) | ((u32)f2b(v.y) << 16);
  p.y = (u32)f2b(v.z) | ((u32)f2b(v.w) << 16);
  ((uint2*)out)[i] = p;
}

// out[c][r] = bf16(in[r][c]);  in: [R][C] fp32. grid (C/32, R/32), block 256.
__global__ void transpose_bf16(const float* __restrict__ in, u16* __restrict__ out,
                               int R, int C) {
  __shared__ float t[32][33];
  int tx = threadIdx.x & 31, ty = threadIdx.x >> 5;
  int r0 = blockIdx.y * 32, c0 = blockIdx.x * 32;
#pragma unroll
  for (int k = 0; k < 4; k++)
    t[ty + 8 * k][tx] = in[(size_t)(r0 + ty + 8 * k) * C + c0 + tx];
  __syncthreads();
#pragma unroll
  for (int k = 0; k < 4; k++)
    out[(size_t)(c0 + ty + 8 * k) * R + r0 + tx] = f2b(t[tx][ty + 8 * k]);
}

// V[bh][s][d] bf16 -> Vt[bh][d][s] bf16. 64x64 tiles. grid (32, 64), block 256.
__global__ void transpose_v(const u16* __restrict__ V, u16* __restrict__ Vt) {
  __shared__ u16 t[64][80];
  int bh = blockIdx.y, s0 = blockIdx.x * 64;
  const u16* Vh = V + (size_t)bh * 2048 * 64;
  u16* Vth = Vt + (size_t)bh * 64 * 2048;
  int tr = threadIdx.x >> 3;            // 0..31
  int tc = (threadIdx.x & 7) * 8;       // 0..56 step 8
#pragma unroll
  for (int p = 0; p < 2; p++) {
    int r = p * 32 + tr;
    *(uint4*)&t[r][tc] = *(const uint4*)(Vh + (size_t)(s0 + r) * 64 + tc);
  }
  __syncthreads();
#pragma unroll
  for (int p = 0; p < 2; p++) {
    int d = p * 32 + tr;
    u16 tmp[8];
#pragma unroll
    for (int k = 0; k < 8; k++) tmp[k] = t[tc + k][d];
    *(uint4*)(Vth + (size_t)d * 2048 + s0 + tc) = *(uint4*)tmp;
  }
}

// ---------------- GEMM kernels (128x128 tile, 16x16x32 bf16 MFMA) ----------------
// Double-buffered LDS staging (1 barrier/tile); XCD swizzle: xcd owns 8 m-tiles
// (A slice 2MB L2-resident), n-tile-major so each B-tile is fetched once/XCD.

__global__ __launch_bounds__(256) void gemm_qkv_kernel(
    const u16* __restrict__ A, const u16* __restrict__ Bt,
    u16* __restrict__ QKV) {   // QKV = 3 x 16MB consecutive [b,h,s,d] buffers
  const int K = 1024;
  __shared__ short8 lA[2][512];   // 16 KB
  __shared__ short8 lB[2][512];   // 16 KB
  int tid = threadIdx.x;
  int w = tid >> 6, l = tid & 63, lr = l & 15, lq = l >> 4;
  int gid = blockIdx.x;
  int xcd = gid & 7, j = gid >> 3;     // 192 blocks per XCD
  int yloc = j & 7, xt = j >> 3;       // y-minor: 8 y per xt before next B-tile
  int m0 = (xcd * 8 + yloc) * 128, n0 = xt * 128;
  int wm = w & 1, wn = w >> 1;
  float4_ acc[4][4] = {};

  const u16* gA0 = A + (size_t)(m0 + w * 32 + lr) * K + lq * 8;
  const u16* gA1 = gA0 + 16 * K;
  const u16* gB0 = Bt + (size_t)(n0 + w * 32 + lr) * K + lq * 8;
  const u16* gB1 = gB0 + 16 * K;

  auto stage = [&](int buf, int k0) {
    async_cp16(gA0 + k0, &lA[buf][(w * 2 + 0) * 64 + l]);
    async_cp16(gA1 + k0, &lA[buf][(w * 2 + 1) * 64 + l]);
    async_cp16(gB0 + k0, &lB[buf][(w * 2 + 0) * 64 + l]);
    async_cp16(gB1 + k0, &lB[buf][(w * 2 + 1) * 64 + l]);
  };
  auto compute = [&](int buf) {
    short8 af[4], bf[4];
#pragma unroll
    for (int t = 0; t < 4; t++) {
      af[t] = lA[buf][(wm * 4 + t) * 64 + l];
      bf[t] = lB[buf][(wn * 4 + t) * 64 + l];
    }
#pragma unroll
    for (int mt = 0; mt < 4; mt++)
#pragma unroll
      for (int nt = 0; nt < 4; nt++)
        acc[mt][nt] = __builtin_amdgcn_mfma_f32_16x16x32_bf16(af[mt], bf[nt], acc[mt][nt], 0, 0, 0);
  };

  stage(0, 0);
  for (int k0 = 0; k0 < K; k0 += 64) {
    __syncthreads();
    stage(1, k0 + 32);                 // k0+32 <= 992 < K always
    compute(0);
    __syncthreads();
    if (k0 + 64 < K) stage(0, k0 + 64);
    compute(1);
  }

  // epilogue: C[row=lq*4+r][col=lr]; col -> (sel,h,d); row -> (b,s)
  const float qsc = 0.18033688011112042f;  // d^-0.5 * log2(e)
#pragma unroll
  for (int nt = 0; nt < 4; nt++) {
    int gn = n0 + wn * 64 + nt * 16 + lr;
    int sel = gn >> 10;
    int h = (gn >> 6) & 15;
    int d = gn & 63;
    float sc = (sel == 0) ? qsc : 1.0f;
    u16* dst = QKV + (size_t)sel * 8388608 + ((size_t)h * 2048) * 64 + d;
#pragma unroll
    for (int mt = 0; mt < 4; mt++) {
#pragma unroll
      for (int r = 0; r < 4; r++) {
        int gm = m0 + wm * 64 + mt * 16 + lq * 4 + r;
        int b = gm >> 11, s = gm & 2047;
        dst[((size_t)b * 16 * 2048 + s) * 64] = f2b(acc[mt][nt][r] * sc);
      }
    }
  }
}

__global__ __launch_bounds__(256) void gemm_out_kernel(
    const u16* __restrict__ A, const u16* __restrict__ Bt,
    const float* __restrict__ bias, float* __restrict__ out) {
  const int K = 1024;
  __shared__ short8 lA[2][512];
  __shared__ short8 lB[2][512];
  int tid = threadIdx.x;
  int w = tid >> 6, l = tid & 63, lr = l & 15, lq = l >> 4;
  int gid = blockIdx.x;
  int xcd = gid & 7, j = gid >> 3;     // 64 blocks per XCD
  int yloc = j & 7, xt = j >> 3;       // 8 y x 8 x per XCD
  int m0 = (xcd * 8 + yloc) * 128, n0 = xt * 128;
  int wm = w & 1, wn = w >> 1;
  float4_ acc[4][4] = {};

  const u16* gA0 = A + (size_t)(m0 + w * 32 + lr) * K + lq * 8;
  const u16* gA1 = gA0 + 16 * K;
  const u16* gB0 = Bt + (size_t)(n0 + w * 32 + lr) * K + lq * 8;
  const u16* gB1 = gB0 + 16 * K;

  auto stage = [&](int buf, int k0) {
    async_cp16(gA0 + k0, &lA[buf][(w * 2 + 0) * 64 + l]);
    async_cp16(gA1 + k0, &lA[buf][(w * 2 + 1) * 64 + l]);
    async_cp16(gB0 + k0, &lB[buf][(w * 2 + 0) * 64 + l]);
    async_cp16(gB1 + k0, &lB[buf][(w * 2 + 1) * 64 + l]);
  };
  auto compute = [&](int buf) {
    short8 af[4], bf[4];
#pragma unroll
    for (int t = 0; t < 4; t++) {
      af[t] = lA[buf][(wm * 4 + t) * 64 + l];
      bf[t] = lB[buf][(wn * 4 + t) * 64 + l];
    }
#pragma unroll
    for (int mt = 0; mt < 4; mt++)
#pragma unroll
      for (int nt = 0; nt < 4; nt++)
        acc[mt][nt] = __builtin_amdgcn_mfma_f32_16x16x32_bf16(af[mt], bf[nt], acc[mt][nt], 0, 0, 0);
  };

  stage(0, 0);
  for (int k0 = 0; k0 < K; k0 += 64) {
    __syncthreads();
    stage(1, k0 + 32);
    compute(0);
    __syncthreads();
    if (k0 + 64 < K) stage(0, k0 + 64);
    compute(1);
  }

#pragma unroll
  for (int nt = 0; nt < 4; nt++) {
    int gn = n0 + wn * 64 + nt * 16 + lr;
    float bv = bias[gn];
#pragma unroll
    for (int mt = 0; mt < 4; mt++)
#pragma unroll
      for (int r = 0; r < 4; r++) {
        int gm = m0 + wm * 64 + mt * 16 + lq * 4 + r;
        out[(size_t)gm * 1024 + gn] = acc[mt][nt][r] + bv;
      }
  }
}

// ---------------- flash attention (block-cooperative, dbuf LDS K/V) ----------------
// Block = 4 waves = 128 q rows (each wave 32 q = 2 groups of 16). KV-step 64,
// double-buffered. K rows staged interleaved (even/odd) -> P packing stays
// 1 v_perm + 1 ds_write_b32. Q pre-scaled by d^-0.5*log2e => P = exp2(S).
// Grid 1024, XCD-swizzled, qblk-major per bh (hot K/V set ~1MB per XCD).

__global__ __launch_bounds__(256) void attn_kernel(
    const u16* __restrict__ Qb, const u16* __restrict__ Kb,
    const u16* __restrict__ Vt, u16* __restrict__ Ob) {
  const int S = 2048, D = 64;
  __shared__ short8 lK[2][512];            // 16 KB
  __shared__ short8 lV[2][512];            // 16 KB
  __shared__ __align__(16) u32 pb[4][16][20];   // 5 KB
  int tid = threadIdx.x;
  int w = tid >> 6, l = tid & 63, lr = l & 15, lq = l >> 4;
  int gid = blockIdx.x;
  int xcd = gid & 7, j = gid >> 3;        // j in [0,128)
  int bh = xcd * 8 + (j >> 4);            // qblk-major: consecutive j share bh
  int qblk = j & 15;                      // 0..15
  int q0 = qblk * 128 + w * 32;
  const u16* Qh = Qb + (size_t)bh * S * D;
  const u16* Kh = Kb + (size_t)bh * S * D;
  const u16* Vh = Vt + (size_t)bh * D * S;

  short8 qf[2][2];
#pragma unroll
  for (int qg = 0; qg < 2; qg++) {
    qf[qg][0] = *(const short8*)(Qh + (q0 + qg * 16 + lr) * D + lq * 8);
    qf[qg][1] = *(const short8*)(Qh + (q0 + qg * 16 + lr) * D + 32 + lq * 8);
  }

  float ls[2][4] = {};
  float4_ o[2][4] = {};

  // staging: K wave w stages rt=w: kv = kv0+(w>>1)*32 + 2*lr + (w&1), d-half w&1? no:
  //   two halves d0/d1 as separate cp16s. V wave w stages dt=w: d = w*16+lr.
  const u16* kg = Kh + (size_t)(((w >> 1) << 5) + 2 * lr + (w & 1)) * D + lq * 8;
  const u16* vg = Vh + (size_t)(w * 16 + lr) * S + lq * 8;

  auto stage = [&](int buf, int kv0) {
    async_cp16(kg + (size_t)kv0 * D, &lK[buf][(w * 2 + 0) * 64 + l]);
    async_cp16(kg + (size_t)kv0 * D + 32, &lK[buf][(w * 2 + 1) * 64 + l]);
    async_cp16(vg + kv0, &lV[buf][(w * 2 + 0) * 64 + l]);
    async_cp16(vg + kv0 + 32, &lV[buf][(w * 2 + 1) * 64 + l]);
  };

  auto compute = [&](int buf) {
#pragma unroll
    for (int sub = 0; sub < 2; sub++) {
      short8 ke0 = lK[buf][((sub * 2 + 0) * 2 + 0) * 64 + l];  // even rows, d 0..31
      short8 ke1 = lK[buf][((sub * 2 + 0) * 2 + 1) * 64 + l];  // even rows, d 32..63
      short8 ko0 = lK[buf][((sub * 2 + 1) * 2 + 0) * 64 + l];  // odd rows,  d 0..31
      short8 ko1 = lK[buf][((sub * 2 + 1) * 2 + 1) * 64 + l];  // odd rows,  d 32..63
#pragma unroll
      for (int qg = 0; qg < 2; qg++) {
        float4_ z = {0.f, 0.f, 0.f, 0.f};
        float4_ s0 = __builtin_amdgcn_mfma_f32_16x16x32_bf16(qf[qg][0], ke0, z, 0, 0, 0);
        s0 = __builtin_amdgcn_mfma_f32_16x16x32_bf16(qf[qg][1], ke1, s0, 0, 0, 0);
        float4_ s1 = __builtin_amdgcn_mfma_f32_16x16x32_bf16(qf[qg][0], ko0, z, 0, 0, 0);
        s1 = __builtin_amdgcn_mfma_f32_16x16x32_bf16(qf[qg][1], ko1, s1, 0, 0, 0);
#pragma unroll
        for (int r = 0; r < 4; r++) {
          float p0 = fexp2(s0[r]);
          float p1 = fexp2(s1[r]);
          u32 pk = pk_trunc(p0, p1);
          // accumulate ROUNDED values so truncation bias cancels at normalize
          ls[qg][r] += __uint_as_float(pk << 16) + __uint_as_float(pk & 0xFFFF0000u);
          pb[w][lq * 4 + r][lr] = pk;
        }
        short8 pa = *(const short8*)&pb[w][lr][lq * 4];  // A-frag: row lr, kv lq*8..+7
#pragma unroll
        for (int dt = 0; dt < 4; dt++)
          o[qg][dt] = __builtin_amdgcn_mfma_f32_16x16x32_bf16(
              pa, lV[buf][(dt * 2 + sub) * 64 + l], o[qg][dt], 0, 0, 0);
      }
    }
  };

  stage(0, 0);
  for (int kv0 = 0; kv0 < S; kv0 += 128) {
    __syncthreads();
    stage(1, kv0 + 64);                 // kv0+64 <= 1984 < S always
    compute(0);
    __syncthreads();
    if (kv0 + 128 < S) stage(0, kv0 + 128);
    compute(1);
  }

  int b = bh >> 4, h = bh & 15;
#pragma unroll
  for (int qg = 0; qg < 2; qg++) {
    float inv[4];
#pragma unroll
    for (int r = 0; r < 4; r++) {
      float s = ls[qg][r];
#pragma unroll
      for (int off = 1; off < 16; off <<= 1) s += __shfl_xor(s, off, 64);
      inv[r] = 1.0f / s;
    }
#pragma unroll
    for (int dt = 0; dt < 4; dt++)
#pragma unroll
      for (int r = 0; r < 4; r++) {
        int s_ = q0 + qg * 16 + lq * 4 + r;
        Ob[((size_t)(b * 2048 + s_)) * 1024 + h * 64 + dt * 16 + lr] =
            f2b(o[qg][dt][r] * inv[r]);
      }
  }
}

// ---------------- launch ----------------

extern "C" void kernel_launch(void* const* d_in, const int* in_sizes, int n_in,
                              void* d_out, int out_size, void* d_ws, size_t ws_size,
                              hipStream_t stream) {
  const float* x     = (const float*)d_in[0];   // [4,2048,1024]
  const float* w_qkv = (const float*)d_in[1];   // [1024,3072]
  const float* w_out = (const float*)d_in[2];   // [1024,1024]
  const float* b_out = (const float*)d_in[3];   // [1024]
  float* out = (float*)d_out;

  char* ws = (char*)d_ws;
  u16* Xb  = (u16*)(ws);                    // 16 MB (x bf16; reused as O)
  u16* Wqt = (u16*)(ws + (16u << 20));      // 6 MB  (w_qkv^T bf16)
  u16* Wot = (u16*)(ws + (22u << 20));      // 2 MB  (w_out^T bf16)
  u16* QKV = (u16*)(ws + (24u << 20));      // 48 MB: Q | K | V  (each [b,h,s,d])
  u16* Qb  = QKV;
  u16* Kb  = QKV + 8388608;
  u16* Vb  = QKV + 16777216;
  u16* Vt  = (u16*)(ws + (72u << 20));      // 16 MB [b,h,d,s] -> 88 MB total
  u16* Ob  = Xb;                            // O overwrites Xb

  cvt_x_bf16<<<8192, 256, 0, stream>>>(x, Xb, 2097152);
  transpose_bf16<<<dim3(96, 32), 256, 0, stream>>>(w_qkv, Wqt, 1024, 3072);
  transpose_bf16<<<dim3(32, 32), 256, 0, stream>>>(w_out, Wot, 1024, 1024);
  gemm_qkv_kernel<<<1536, 256, 0, stream>>>(Xb, Wqt, QKV);
  transpose_v<<<dim3(32, 64), 256, 0, stream>>>(Vb, Vt);
  attn_kernel<<<1024, 256, 0, stream>>>(Qb, Kb, Vt, Ob);
  gemm_out_kernel<<<512, 256, 0, stream>>>(Ob, Wot, b_out, out);
}

// Round 7
// 343.301 us; speedup vs baseline: 1.0208x; 1.0208x over previous
//
#include <hip/hip_runtime.h>
#include <cstdint>
#include <cstddef>

// MI355X self-attention: B=4 S=2048 E=1024 H=16 D=64
// R7: diagnostic round. attn split into 2 launches (bh halves) so gemm_qkv
//     surfaces in rocprof top-5 next round; prepass fused into one kernel;
//     attn ls-accum via v_dot2_f32_bf16 (guarded). gemm kernels byte-identical
//     to R6 so their counters diagnose the R6 structure.

typedef __attribute__((ext_vector_type(8))) short short8;   // 8 x bf16
typedef __attribute__((ext_vector_type(4))) float float4_;
typedef unsigned int u32;
typedef unsigned short u16;

__device__ __forceinline__ u16 f2b(float f) {
  u32 u = __float_as_uint(f);
  u += 0x7FFFu + ((u >> 16) & 1u);   // RNE
  return (u16)(u >> 16);
}

__device__ __forceinline__ float fexp2(float x) {
#if __has_builtin(__builtin_amdgcn_exp2f)
  return __builtin_amdgcn_exp2f(x);   // bare v_exp_f32
#else
  return exp2f(x);
#endif
}

// pack (lo,hi) floats -> bf16x2 by truncation (1 v_perm)
__device__ __forceinline__ u32 pk_trunc(float lo, float hi) {
#if __has_builtin(__builtin_amdgcn_perm)
  return __builtin_amdgcn_perm(__float_as_uint(hi), __float_as_uint(lo), 0x07060302);
#else
  return (__float_as_uint(hi) & 0xFFFF0000u) | (__float_as_uint(lo) >> 16);
#endif
}

// acc += sum of the two bf16s in pk (rounded values, so truncation bias
// cancels at normalization). v_dot2_f32_bf16 if available (1 instr), else 4.
#if __has_builtin(__builtin_amdgcn_fdot2_f32_bf16)
typedef __bf16 bf16x2 __attribute__((ext_vector_type(2)));
__device__ __forceinline__ float accum_pk(u32 pk, float acc) {
  bf16x2 p = __builtin_bit_cast(bf16x2, pk);
  bf16x2 one = __builtin_bit_cast(bf16x2, (u32)0x3F803F80u);
  return __builtin_amdgcn_fdot2_f32_bf16(p, one, acc, false);
}
#else
__device__ __forceinline__ float accum_pk(u32 pk, float acc) {
  return acc + __uint_as_float(pk << 16) + __uint_as_float(pk & 0xFFFF0000u);
}
#endif

// async global->LDS, 16B per lane; LDS dst must be wave-uniform base + lane*16
__device__ __forceinline__ void async_cp16(const void* g, void* l) {
  __builtin_amdgcn_global_load_lds(
      (const __attribute__((address_space(1))) u32*)g,
      (__attribute__((address_space(3))) u32*)l, 16, 0, 0);
}

// ---------------- fused pre-pass ----------------
// blocks [0,8192): cvt x->bf16; [8192,11264): transpose w_qkv; rest: w_out.

__device__ __forceinline__ void transpose_block(const float* __restrict__ in,
                                                u16* __restrict__ out,
                                                int R, int C, int bx, int by,
                                                float t[32][33]) {
  int tx = threadIdx.x & 31, ty = threadIdx.x >> 5;
  int r0 = by * 32, c0 = bx * 32;
#pragma unroll
  for (int k = 0; k < 4; k++)
    t[ty + 8 * k][tx] = in[(size_t)(r0 + ty + 8 * k) * C + c0 + tx];
  __syncthreads();
#pragma unroll
  for (int k = 0; k < 4; k++)
    out[(size_t)(c0 + ty + 8 * k) * R + r0 + tx] = f2b(t[tx][ty + 8 * k]);
}

__global__ void prepass_kernel(const float* __restrict__ x, u16* __restrict__ Xb,
                               const float* __restrict__ wqkv, u16* __restrict__ Wqt,
                               const float* __restrict__ wout, u16* __restrict__ Wot) {
  __shared__ float t[32][33];
  int gid = blockIdx.x;
  if (gid < 8192) {
    int i = gid * 256 + threadIdx.x;
    float4 v = ((const float4*)x)[i];
    uint2 p;
    p.x = (u32)f2b(v.x) | ((u32)f2b(v.y) << 16);
    p.y = (u32)f2b(v.z) | ((u32)f2b(v.w) << 16);
    ((uint2*)Xb)[i] = p;
  } else if (gid < 11264) {
    int j = gid - 8192;
    transpose_block(wqkv, Wqt, 1024, 3072, j % 96, j / 96, t);
  } else {
    int j = gid - 11264;
    transpose_block(wout, Wot, 1024, 1024, j % 32, j / 32, t);
  }
}

// V[bh][s][d] bf16 -> Vt[bh][d][s] bf16. 64x64 tiles. grid (32, 64), block 256.
__global__ void transpose_v(const u16* __restrict__ V, u16* __restrict__ Vt) {
  __shared__ u16 t[64][80];
  int bh = blockIdx.y, s0 = blockIdx.x * 64;
  const u16* Vh = V + (size_t)bh * 2048 * 64;
  u16* Vth = Vt + (size_t)bh * 64 * 2048;
  int tr = threadIdx.x >> 3;            // 0..31
  int tc = (threadIdx.x & 7) * 8;       // 0..56 step 8
#pragma unroll
  for (int p = 0; p < 2; p++) {
    int r = p * 32 + tr;
    *(uint4*)&t[r][tc] = *(const uint4*)(Vh + (size_t)(s0 + r) * 64 + tc);
  }
  __syncthreads();
#pragma unroll
  for (int p = 0; p < 2; p++) {
    int d = p * 32 + tr;
    u16 tmp[8];
#pragma unroll
    for (int k = 0; k < 8; k++) tmp[k] = t[tc + k][d];
    *(uint4*)(Vth + (size_t)d * 2048 + s0 + tc) = *(uint4*)tmp;
  }
}

// ---------------- GEMM kernels (128x128 tile, 16x16x32 bf16 MFMA) ----------------
// UNCHANGED from R6 (so next round's counters diagnose this exact structure).

__global__ __launch_bounds__(256) void gemm_qkv_kernel(
    const u16* __restrict__ A, const u16* __restrict__ Bt,
    u16* __restrict__ QKV) {   // QKV = 3 x 16MB consecutive [b,h,s,d] buffers
  const int K = 1024;
  __shared__ short8 lA[2][512];   // 16 KB
  __shared__ short8 lB[2][512];   // 16 KB
  int tid = threadIdx.x;
  int w = tid >> 6, l = tid & 63, lr = l & 15, lq = l >> 4;
  int gid = blockIdx.x;
  int xcd = gid & 7, j = gid >> 3;     // 192 blocks per XCD
  int yloc = j & 7, xt = j >> 3;       // y-minor: 8 y per xt before next B-tile
  int m0 = (xcd * 8 + yloc) * 128, n0 = xt * 128;
  int wm = w & 1, wn = w >> 1;
  float4_ acc[4][4] = {};

  const u16* gA0 = A + (size_t)(m0 + w * 32 + lr) * K + lq * 8;
  const u16* gA1 = gA0 + 16 * K;
  const u16* gB0 = Bt + (size_t)(n0 + w * 32 + lr) * K + lq * 8;
  const u16* gB1 = gB0 + 16 * K;

  auto stage = [&](int buf, int k0) {
    async_cp16(gA0 + k0, &lA[buf][(w * 2 + 0) * 64 + l]);
    async_cp16(gA1 + k0, &lA[buf][(w * 2 + 1) * 64 + l]);
    async_cp16(gB0 + k0, &lB[buf][(w * 2 + 0) * 64 + l]);
    async_cp16(gB1 + k0, &lB[buf][(w * 2 + 1) * 64 + l]);
  };
  auto compute = [&](int buf) {
    short8 af[4], bf[4];
#pragma unroll
    for (int t = 0; t < 4; t++) {
      af[t] = lA[buf][(wm * 4 + t) * 64 + l];
      bf[t] = lB[buf][(wn * 4 + t) * 64 + l];
    }
#pragma unroll
    for (int mt = 0; mt < 4; mt++)
#pragma unroll
      for (int nt = 0; nt < 4; nt++)
        acc[mt][nt] = __builtin_amdgcn_mfma_f32_16x16x32_bf16(af[mt], bf[nt], acc[mt][nt], 0, 0, 0);
  };

  stage(0, 0);
  for (int k0 = 0; k0 < K; k0 += 64) {
    __syncthreads();
    stage(1, k0 + 32);
    compute(0);
    __syncthreads();
    if (k0 + 64 < K) stage(0, k0 + 64);
    compute(1);
  }

  const float qsc = 0.18033688011112042f;  // d^-0.5 * log2(e)
#pragma unroll
  for (int nt = 0; nt < 4; nt++) {
    int gn = n0 + wn * 64 + nt * 16 + lr;
    int sel = gn >> 10;
    int h = (gn >> 6) & 15;
    int d = gn & 63;
    float sc = (sel == 0) ? qsc : 1.0f;
    u16* dst = QKV + (size_t)sel * 8388608 + ((size_t)h * 2048) * 64 + d;
#pragma unroll
    for (int mt = 0; mt < 4; mt++) {
#pragma unroll
      for (int r = 0; r < 4; r++) {
        int gm = m0 + wm * 64 + mt * 16 + lq * 4 + r;
        int b = gm >> 11, s = gm & 2047;
        dst[((size_t)b * 16 * 2048 + s) * 64] = f2b(acc[mt][nt][r] * sc);
      }
    }
  }
}

__global__ __launch_bounds__(256) void gemm_out_kernel(
    const u16* __restrict__ A, const u16* __restrict__ Bt,
    const float* __restrict__ bias, float* __restrict__ out) {
  const int K = 1024;
  __shared__ short8 lA[2][512];
  __shared__ short8 lB[2][512];
  int tid = threadIdx.x;
  int w = tid >> 6, l = tid & 63, lr = l & 15, lq = l >> 4;
  int gid = blockIdx.x;
  int xcd = gid & 7, j = gid >> 3;     // 64 blocks per XCD
  int yloc = j & 7, xt = j >> 3;       // 8 y x 8 x per XCD
  int m0 = (xcd * 8 + yloc) * 128, n0 = xt * 128;
  int wm = w & 1, wn = w >> 1;
  float4_ acc[4][4] = {};

  const u16* gA0 = A + (size_t)(m0 + w * 32 + lr) * K + lq * 8;
  const u16* gA1 = gA0 + 16 * K;
  const u16* gB0 = Bt + (size_t)(n0 + w * 32 + lr) * K + lq * 8;
  const u16* gB1 = gB0 + 16 * K;

  auto stage = [&](int buf, int k0) {
    async_cp16(gA0 + k0, &lA[buf][(w * 2 + 0) * 64 + l]);
    async_cp16(gA1 + k0, &lA[buf][(w * 2 + 1) * 64 + l]);
    async_cp16(gB0 + k0, &lB[buf][(w * 2 + 0) * 64 + l]);
    async_cp16(gB1 + k0, &lB[buf][(w * 2 + 1) * 64 + l]);
  };
  auto compute = [&](int buf) {
    short8 af[4], bf[4];
#pragma unroll
    for (int t = 0; t < 4; t++) {
      af[t] = lA[buf][(wm * 4 + t) * 64 + l];
      bf[t] = lB[buf][(wn * 4 + t) * 64 + l];
    }
#pragma unroll
    for (int mt = 0; mt < 4; mt++)
#pragma unroll
      for (int nt = 0; nt < 4; nt++)
        acc[mt][nt] = __builtin_amdgcn_mfma_f32_16x16x32_bf16(af[mt], bf[nt], acc[mt][nt], 0, 0, 0);
  };

  stage(0, 0);
  for (int k0 = 0; k0 < K; k0 += 64) {
    __syncthreads();
    stage(1, k0 + 32);
    compute(0);
    __syncthreads();
    if (k0 + 64 < K) stage(0, k0 + 64);
    compute(1);
  }

#pragma unroll
  for (int nt = 0; nt < 4; nt++) {
    int gn = n0 + wn * 64 + nt * 16 + lr;
    float bv = bias[gn];
#pragma unroll
    for (int mt = 0; mt < 4; mt++)
#pragma unroll
      for (int r = 0; r < 4; r++) {
        int gm = m0 + wm * 64 + mt * 16 + lq * 4 + r;
        out[(size_t)gm * 1024 + gn] = acc[mt][nt][r] + bv;
      }
  }
}

// ---------------- flash attention (block-cooperative, dbuf LDS K/V) ----------------
// Launched twice (bh halves) so gemm_qkv surfaces in rocprof top-5.
// Block = 4 waves = 128 q rows. KV-step 64, double-buffered. K rows staged
// interleaved (even/odd). Q pre-scaled by d^-0.5*log2e => P = exp2(S).
// Grid 512/launch, XCD-swizzled: each XCD owns 4 bh, qblk-major.

__global__ __launch_bounds__(256) void attn_kernel(
    const u16* __restrict__ Qb, const u16* __restrict__ Kb,
    const u16* __restrict__ Vt, u16* __restrict__ Ob, int bh_base) {
  const int S = 2048, D = 64;
  __shared__ short8 lK[2][512];            // 16 KB
  __shared__ short8 lV[2][512];            // 16 KB
  __shared__ __align__(16) u32 pb[4][16][20];   // 5 KB
  int tid = threadIdx.x;
  int w = tid >> 6, l = tid & 63, lr = l & 15, lq = l >> 4;
  int gid = blockIdx.x;
  int xcd = gid & 7, j = gid >> 3;        // j in [0,64)
  int bh = bh_base + xcd * 4 + (j >> 4);  // qblk-major: consecutive j share bh
  int qblk = j & 15;                      // 0..15
  int q0 = qblk * 128 + w * 32;
  const u16* Qh = Qb + (size_t)bh * S * D;
  const u16* Kh = Kb + (size_t)bh * S * D;
  const u16* Vh = Vt + (size_t)bh * D * S;

  short8 qf[2][2];
#pragma unroll
  for (int qg = 0; qg < 2; qg++) {
    qf[qg][0] = *(const short8*)(Qh + (q0 + qg * 16 + lr) * D + lq * 8);
    qf[qg][1] = *(const short8*)(Qh + (q0 + qg * 16 + lr) * D + 32 + lq * 8);
  }

  float ls[2][4] = {};
  float4_ o[2][4] = {};

  const u16* kg = Kh + (size_t)(((w >> 1) << 5) + 2 * lr + (w & 1)) * D + lq * 8;
  const u16* vg = Vh + (size_t)(w * 16 + lr) * S + lq * 8;

  auto stage = [&](int buf, int kv0) {
    async_cp16(kg + (size_t)kv0 * D, &lK[buf][(w * 2 + 0) * 64 + l]);
    async_cp16(kg + (size_t)kv0 * D + 32, &lK[buf][(w * 2 + 1) * 64 + l]);
    async_cp16(vg + kv0, &lV[buf][(w * 2 + 0) * 64 + l]);
    async_cp16(vg + kv0 + 32, &lV[buf][(w * 2 + 1) * 64 + l]);
  };

  auto compute = [&](int buf) {
#pragma unroll
    for (int sub = 0; sub < 2; sub++) {
      short8 ke0 = lK[buf][((sub * 2 + 0) * 2 + 0) * 64 + l];  // even rows, d 0..31
      short8 ke1 = lK[buf][((sub * 2 + 0) * 2 + 1) * 64 + l];  // even rows, d 32..63
      short8 ko0 = lK[buf][((sub * 2 + 1) * 2 + 0) * 64 + l];  // odd rows,  d 0..31
      short8 ko1 = lK[buf][((sub * 2 + 1) * 2 + 1) * 64 + l];  // odd rows,  d 32..63
#pragma unroll
      for (int qg = 0; qg < 2; qg++) {
        float4_ z = {0.f, 0.f, 0.f, 0.f};
        float4_ s0 = __builtin_amdgcn_mfma_f32_16x16x32_bf16(qf[qg][0], ke0, z, 0, 0, 0);
        s0 = __builtin_amdgcn_mfma_f32_16x16x32_bf16(qf[qg][1], ke1, s0, 0, 0, 0);
        float4_ s1 = __builtin_amdgcn_mfma_f32_16x16x32_bf16(qf[qg][0], ko0, z, 0, 0, 0);
        s1 = __builtin_amdgcn_mfma_f32_16x16x32_bf16(qf[qg][1], ko1, s1, 0, 0, 0);
#pragma unroll
        for (int r = 0; r < 4; r++) {
          float p0 = fexp2(s0[r]);
          float p1 = fexp2(s1[r]);
          u32 pk = pk_trunc(p0, p1);
          ls[qg][r] = accum_pk(pk, ls[qg][r]);  // rounded values: bias cancels
          pb[w][lq * 4 + r][lr] = pk;
        }
        short8 pa = *(const short8*)&pb[w][lr][lq * 4];  // A-frag: row lr, kv lq*8..+7
#pragma unroll
        for (int dt = 0; dt < 4; dt++)
          o[qg][dt] = __builtin_amdgcn_mfma_f32_16x16x32_bf16(
              pa, lV[buf][(dt * 2 + sub) * 64 + l], o[qg][dt], 0, 0, 0);
      }
    }
  };

  stage(0, 0);
  for (int kv0 = 0; kv0 < S; kv0 += 128) {
    __syncthreads();
    stage(1, kv0 + 64);
    compute(0);
    __syncthreads();
    if (kv0 + 128 < S) stage(0, kv0 + 128);
    compute(1);
  }

  int b = bh >> 4, h = bh & 15;
#pragma unroll
  for (int qg = 0; qg < 2; qg++) {
    float inv[4];
#pragma unroll
    for (int r = 0; r < 4; r++) {
      float s = ls[qg][r];
#pragma unroll
      for (int off = 1; off < 16; off <<= 1) s += __shfl_xor(s, off, 64);
      inv[r] = 1.0f / s;
    }
#pragma unroll
    for (int dt = 0; dt < 4; dt++)
#pragma unroll
      for (int r = 0; r < 4; r++) {
        int s_ = q0 + qg * 16 + lq * 4 + r;
        Ob[((size_t)(b * 2048 + s_)) * 1024 + h * 64 + dt * 16 + lr] =
            f2b(o[qg][dt][r] * inv[r]);
      }
  }
}

// ---------------- launch ----------------

extern "C" void kernel_launch(void* const* d_in, const int* in_sizes, int n_in,
                              void* d_out, int out_size, void* d_ws, size_t ws_size,
                              hipStream_t stream) {
  const float* x     = (const float*)d_in[0];   // [4,2048,1024]
  const float* w_qkv = (const float*)d_in[1];   // [1024,3072]
  const float* w_out = (const float*)d_in[2];   // [1024,1024]
  const float* b_out = (const float*)d_in[3];   // [1024]
  float* out = (float*)d_out;

  char* ws = (char*)d_ws;
  u16* Xb  = (u16*)(ws);                    // 16 MB (x bf16; reused as O)
  u16* Wqt = (u16*)(ws + (16u << 20));      // 6 MB  (w_qkv^T bf16)
  u16* Wot = (u16*)(ws + (22u << 20));      // 2 MB  (w_out^T bf16)
  u16* QKV = (u16*)(ws + (24u << 20));      // 48 MB: Q | K | V  (each [b,h,s,d])
  u16* Qb  = QKV;
  u16* Kb  = QKV + 8388608;
  u16* Vb  = QKV + 16777216;
  u16* Vt  = (u16*)(ws + (72u << 20));      // 16 MB [b,h,d,s] -> 88 MB total
  u16* Ob  = Xb;                            // O overwrites Xb

  prepass_kernel<<<12288, 256, 0, stream>>>(x, Xb, w_qkv, Wqt, w_out, Wot);
  gemm_qkv_kernel<<<1536, 256, 0, stream>>>(Xb, Wqt, QKV);
  transpose_v<<<dim3(32, 64), 256, 0, stream>>>(Vb, Vt);
  attn_kernel<<<512, 256, 0, stream>>>(Qb, Kb, Vt, Ob, 0);
  attn_kernel<<<512, 256, 0, stream>>>(Qb, Kb, Vt, Ob, 32);
  gemm_out_kernel<<<512, 256, 0, stream>>>(Ob, Wot, b_out, out);
}